// Round 1
// baseline (890.638 us; speedup 1.0000x reference)
//
#include <hip/hip_runtime.h>
#include <hip/hip_bf16.h>
#include <stdint.h>

typedef __bf16 bf16;
typedef __bf16 bf16x4 __attribute__((ext_vector_type(4)));
typedef __bf16 bf16x8 __attribute__((ext_vector_type(8)));
typedef float floatx4 __attribute__((ext_vector_type(4)));

#define T_TOK 8192
#define DIM 2048
#define NE 8
#define NT (DIM / 64)      // 32 K-tiles of BK=64
#define MAX_CHUNKS 72      // sum ceil(ne/256) <= 64+8
#define PROJ_CIDS 32       // 8192/256

// ---- async global->LDS 16B. Per-lane global address free; LDS dest is
//      wave-uniform base + lane*16 (our layout is linear in tid). ----
__device__ inline void gld_lds16(const bf16* g, bf16* l) {
  __builtin_amdgcn_global_load_lds(
      (const __attribute__((address_space(1))) uint32_t*)g,
      (__attribute__((address_space(3))) uint32_t*)l, 16, 0, 0);
}

// ---- transpose [Dk,Dn] fp32 -> [Dn,Dk] bf16, batched over blockIdx.z ----
__global__ __launch_bounds__(256) void transpose_convert(
    const float* __restrict__ in, bf16* __restrict__ out) {
  __shared__ float tile[32][33];
  const int tx = threadIdx.x & 31;
  const int ty = threadIdx.x >> 5;
  const int n0 = blockIdx.x * 32;
  const int k0 = blockIdx.y * 32;
  const size_t base = (size_t)blockIdx.z * DIM * DIM;
  const float* src = in + base;
  bf16* dst = out + base;
#pragma unroll
  for (int i = 0; i < 32; i += 8)
    tile[ty + i][tx] = src[(size_t)(k0 + ty + i) * DIM + n0 + tx];
  __syncthreads();
#pragma unroll
  for (int i = 0; i < 32; i += 8)
    dst[(size_t)(n0 + ty + i) * DIM + k0 + tx] = (bf16)tile[tx][ty + i];
}

// ---- router (fused x->bf16): logits, top-2 (strict >, lower idx wins ties),
//      softmax gates, scatter (assign_id, gate) into per-expert lists ----
__global__ __launch_bounds__(256) void router_kernel(
    const float* __restrict__ x, const float* __restrict__ Wr,
    const float* __restrict__ br, int* __restrict__ cnt,
    int* __restrict__ aid_list, float* __restrict__ gate_list,
    bf16* __restrict__ xb) {
  const int t = blockIdx.x;
  const int tid = threadIdx.x;
  const float* xr = x + (size_t)t * DIM;
  bf16* xbr = xb + (size_t)t * DIM;
  float acc[8];
#pragma unroll
  for (int e = 0; e < 8; ++e) acc[e] = 0.f;
#pragma unroll
  for (int h = 0; h < 2; ++h) {
    const int d0 = tid * 4 + h * 1024;
    float4 xv = *(const float4*)&xr[d0];
    bf16x4 xc;
    xc[0] = (bf16)xv.x; xc[1] = (bf16)xv.y; xc[2] = (bf16)xv.z; xc[3] = (bf16)xv.w;
    *(bf16x4*)&xbr[d0] = xc;
    const float* wp = &Wr[(size_t)d0 * NE];
    float xe[4] = {xv.x, xv.y, xv.z, xv.w};
#pragma unroll
    for (int q = 0; q < 4; ++q) {
      float4 w0 = *(const float4*)&wp[q * 8];
      float4 w1 = *(const float4*)&wp[q * 8 + 4];
      acc[0] += xe[q] * w0.x; acc[1] += xe[q] * w0.y;
      acc[2] += xe[q] * w0.z; acc[3] += xe[q] * w0.w;
      acc[4] += xe[q] * w1.x; acc[5] += xe[q] * w1.y;
      acc[6] += xe[q] * w1.z; acc[7] += xe[q] * w1.w;
    }
  }
#pragma unroll
  for (int e = 0; e < 8; ++e) {
#pragma unroll
    for (int off = 32; off > 0; off >>= 1) acc[e] += __shfl_down(acc[e], off, 64);
  }
  __shared__ float red[4][8];
  const int lane = tid & 63, wid = tid >> 6;
  if (lane == 0) {
#pragma unroll
    for (int e = 0; e < 8; ++e) red[wid][e] = acc[e];
  }
  __syncthreads();
  if (tid == 0) {
    float lg[8];
#pragma unroll
    for (int e = 0; e < 8; ++e)
      lg[e] = red[0][e] + red[1][e] + red[2][e] + red[3][e] + br[e];
    int i0 = 0;
#pragma unroll
    for (int e = 1; e < 8; ++e) if (lg[e] > lg[i0]) i0 = e;
    int i1 = (i0 == 0) ? 1 : 0;
#pragma unroll
    for (int e = 0; e < 8; ++e)
      if (e != i0 && lg[e] > lg[i1]) i1 = e;
    const float g0 = 1.f / (1.f + expf(lg[i1] - lg[i0]));
    const float g1 = 1.f - g0;
    int p0 = atomicAdd(&cnt[i0], 1);
    aid_list[i0 * T_TOK + p0] = t * 2;
    gate_list[i0 * T_TOK + p0] = g0;
    int p1 = atomicAdd(&cnt[i1], 1);
    aid_list[i1 * T_TOK + p1] = t * 2 + 1;
    gate_list[i1 * T_TOK + p1] = g1;
  }
}

// ---- build compact (expert, m0) chunk table (256-row chunks) ----
__global__ void build_chunks(const int* __restrict__ cnt, int2* __restrict__ chunks,
                             int* __restrict__ nchunks) {
  if (threadIdx.x == 0 && blockIdx.x == 0) {
    int tot = 0;
#pragma unroll
    for (int e = 0; e < NE; ++e) {
      const int ne = cnt[e];
      for (int m0 = 0; m0 < ne; m0 += 256) chunks[tot++] = make_int2(e, m0);
    }
    *nchunks = tot;
  }
}

// ===========================================================================
// 256x256 tile, BK=64, 512 threads (2x4 waves, 128x64 per wave), double-
// buffered 128 KiB LDS, 4 phases per K-tile, COUNTED vmcnt (never 0 in the
// main loop), raw s_barrier + setprio around MFMA clusters.
//
// LDS tiles [256 rows][64 k] bf16, 16B chunks with XOR swizzle: row r,
// k-block kb stored at position kb^(r&7) -> elem offset r*64 + ((kb^(r&7))*8).
// Staged via linear-dest global_load_lds with pre-swizzled global k offset.
// Fragment read (row mi, kb): since mi&7 == l15&7 for all frags of a lane,
// offset = (wrow + l15)*64 + ((kb ^ (l15&7))*8) + i*1024  -> conflict-free.
// ===========================================================================

// phases of one K-tile: (s=kstep, mh=m-half). bfr loaded at mh==0, reused.
#define GEMM_TILE_PHASES(STAGE_EXPR)                                          \
  {                                                                           \
    bf16x8 af[4], bfr[4];                                                     \
_Pragma("unroll")                                                             \
    for (int s = 0; s < 2; ++s) {                                             \
      const int xo = s ? x1 : x0;                                             \
_Pragma("unroll")                                                             \
      for (int mh = 0; mh < 2; ++mh) {                                        \
        if (mh == 0) {                                                        \
_Pragma("unroll")                                                             \
          for (int j = 0; j < 4; ++j)                                         \
            bfr[j] = *(const bf16x8*)&bsF[bbase + xo + j * 1024];             \
        }                                                                     \
_Pragma("unroll")                                                             \
        for (int i = 0; i < 4; ++i)                                           \
          af[i] = *(const bf16x8*)&asF[abase + xo + (mh * 4 + i) * 1024];     \
        const int ph = s * 2 + mh;                                            \
        if ((STAGE_EXPR) && ph < 3) {                                         \
          const int h = ph + 1;                                               \
          gld_lds16(ap[h] + kn, asN + (size_t)(tid + 512 * h) * 8);           \
          gld_lds16(bp[h] + kn, bsN + (size_t)(tid + 512 * h) * 8);           \
        }                                                                     \
        __builtin_amdgcn_s_setprio(1);                                        \
_Pragma("unroll")                                                             \
        for (int i = 0; i < 4; ++i)                                           \
_Pragma("unroll")                                                             \
          for (int j = 0; j < 4; ++j)                                         \
            acc[mh * 4 + i][j] = __builtin_amdgcn_mfma_f32_16x16x32_bf16(     \
                af[i], bfr[j], acc[mh * 4 + i][j], 0, 0, 0);                  \
        __builtin_amdgcn_s_setprio(0);                                        \
      }                                                                       \
    }                                                                         \
  }

// ---- grouped expert GEMM: H = silu(Xg @ We[e]^T-layout + be[e]) * gate ----
__global__ __launch_bounds__(512, 2) void expert_gemm(
    const bf16* __restrict__ xb, const bf16* __restrict__ Wt,
    const float* __restrict__ be, const int* __restrict__ cnt,
    const int* __restrict__ aid_list, const float* __restrict__ gate_list,
    const int2* __restrict__ chunks, const int* __restrict__ nchunks,
    bf16* __restrict__ aout) {
  // XCD-contiguous remap: XCD k gets wg in [k*MAX_CHUNKS, (k+1)*MAX_CHUNKS):
  // consecutive wg share cid (A-tile + expert B panels reuse in that L2).
  int wg = blockIdx.x;
  wg = (wg & 7) * MAX_CHUNKS + (wg >> 3);
  const int cid = wg >> 3;
  if (cid >= *nchunks) return;
  const int2 ch = chunks[cid];
  const int e = ch.x;
  const int m0 = ch.y;
  const int ne = cnt[e];
  const int n0 = (wg & 7) * 256;
  const int tid = threadIdx.x;

  __shared__ bf16 As[2][256 * 64];
  __shared__ bf16 Bs[2][256 * 64];
  __shared__ int aidS[256];
  __shared__ float gateS[256];

  if (tid < 256) {
    const int idx = m0 + tid;
    aidS[tid] = (idx < ne) ? aid_list[e * T_TOK + idx] : 0;
    gateS[tid] = (idx < ne) ? gate_list[e * T_TOK + idx] : 0.f;
  }
  __syncthreads();

  // staging: pass h covers rows h*64 + (tid>>3), position tid&7 holds
  // k-block (tid&7)^(row&7) -> pre-swizzled global k offset kq.
  const int r0 = tid >> 3;
  const int kq = ((tid & 7) ^ (r0 & 7)) * 8;
  const bf16* wbase = Wt + (size_t)e * DIM * DIM;
  const bf16* ap[4];
  const bf16* bp[4];
#pragma unroll
  for (int h = 0; h < 4; ++h) {
    const int r = r0 + 64 * h;
    ap[h] = xb + (size_t)(aidS[r] >> 1) * DIM + kq;
    bp[h] = wbase + (size_t)(n0 + r) * DIM + kq;
  }

  const int lane = tid & 63, w = tid >> 6;
  const int wm = w >> 2, wn = w & 3;          // 2 x 4 waves
  const int quad = lane >> 4, l15 = lane & 15;
  const int x0 = ((quad) ^ (l15 & 7)) * 8;        // kstep 0: kb = quad
  const int x1 = ((quad + 4) ^ (l15 & 7)) * 8;    // kstep 1: kb = quad+4
  const int abase = (wm * 128 + l15) * 64;
  const int bbase = (wn * 64 + l15) * 64;

  floatx4 acc[8][4];
#pragma unroll
  for (int i = 0; i < 8; ++i)
#pragma unroll
    for (int j = 0; j < 4; ++j) acc[i][j] = (floatx4){0.f, 0.f, 0.f, 0.f};

  // prologue: tile 0 -> buf 0 (8 loads in flight entering the loop)
#pragma unroll
  for (int h = 0; h < 4; ++h) {
    gld_lds16(ap[h], &As[0][(size_t)(tid + 512 * h) * 8]);
    gld_lds16(bp[h], &Bs[0][(size_t)(tid + 512 * h) * 8]);
  }

  int p = 0;
  for (int t = 0; t < NT; ++t) {
    const bf16* asF = &As[p][0];
    const bf16* bsF = &Bs[p][0];
    bf16* asN = &As[p ^ 1][0];
    bf16* bsN = &Bs[p ^ 1][0];
    const int kn = (t + 1) * 64;
    const bool stage = (t + 1 < NT);

    asm volatile("" ::: "memory");
    __builtin_amdgcn_s_barrier();   // all waves done reading buf[p^1] (tile t-1)
    if (stage) {
      // issue first pair for tile t+1, then COUNTED drain of tile t's 8 loads
      gld_lds16(ap[0] + kn, asN + (size_t)tid * 8);
      gld_lds16(bp[0] + kn, bsN + (size_t)tid * 8);
      asm volatile("s_waitcnt vmcnt(2)" ::: "memory");
    } else {
      asm volatile("s_waitcnt vmcnt(0)" ::: "memory");
    }
    __builtin_amdgcn_s_barrier();   // tile t fully resident for every wave
    asm volatile("" ::: "memory");

    GEMM_TILE_PHASES(stage)
    p ^= 1;
  }

  // epilogue: + be, silu, * gate, scatter bf16 to assignment row
#pragma unroll
  for (int j = 0; j < 4; ++j) {
    const int col = n0 + wn * 64 + j * 16 + l15;
    const float bev = be[e * DIM + col];
#pragma unroll
    for (int i = 0; i < 8; ++i) {
#pragma unroll
      for (int r = 0; r < 4; ++r) {
        const int rl = wm * 128 + i * 16 + quad * 4 + r;
        if (m0 + rl < ne) {
          float v = acc[i][j][r] + bev;
          v = v / (1.f + __expf(-v));
          v *= gateS[rl];
          aout[(size_t)aidS[rl] * DIM + col] = (bf16)v;
        }
      }
    }
  }
}

// ---- combine slot pairs: hcomb[t] = aout[2t] + aout[2t+1] (bf16) ----
__global__ __launch_bounds__(256) void combine_kernel(
    const bf16* __restrict__ aout, bf16* __restrict__ hcomb) {
  const size_t i = ((size_t)blockIdx.x * 256 + threadIdx.x) * 8;
  const size_t row = i >> 11;
  const size_t d = i & 2047;
  const bf16* a0 = aout + (row << 12) + d;
  bf16x8 u0 = *(const bf16x8*)a0;
  bf16x8 u1 = *(const bf16x8*)(a0 + DIM);
  bf16x8 s;
#pragma unroll
  for (int q = 0; q < 8; ++q) s[q] = (bf16)((float)u0[q] + (float)u1[q]);
  *(bf16x8*)&hcomb[i] = s;
}

// ---- output projection: hcomb @ Wo + bo + x -> y (fp32), same 256^2 core ----
__global__ __launch_bounds__(512, 2) void proj_gemm(
    const bf16* __restrict__ hcomb, const bf16* __restrict__ Wot,
    const float* __restrict__ bo, const float* __restrict__ x,
    float* __restrict__ y) {
  int wg = blockIdx.x;
  wg = (wg & 7) * PROJ_CIDS + (wg >> 3);
  const int m0 = (wg >> 3) * 256;
  const int n0 = (wg & 7) * 256;
  const int tid = threadIdx.x;

  __shared__ bf16 As[2][256 * 64];
  __shared__ bf16 Bs[2][256 * 64];

  const int r0 = tid >> 3;
  const int kq = ((tid & 7) ^ (r0 & 7)) * 8;
  const bf16* ap[4];
  const bf16* bp[4];
#pragma unroll
  for (int h = 0; h < 4; ++h) {
    const int r = r0 + 64 * h;
    ap[h] = hcomb + (size_t)(m0 + r) * DIM + kq;
    bp[h] = Wot + (size_t)(n0 + r) * DIM + kq;
  }

  const int lane = tid & 63, w = tid >> 6;
  const int wm = w >> 2, wn = w & 3;
  const int quad = lane >> 4, l15 = lane & 15;
  const int x0 = ((quad) ^ (l15 & 7)) * 8;
  const int x1 = ((quad + 4) ^ (l15 & 7)) * 8;
  const int abase = (wm * 128 + l15) * 64;
  const int bbase = (wn * 64 + l15) * 64;

  floatx4 acc[8][4];
#pragma unroll
  for (int i = 0; i < 8; ++i)
#pragma unroll
    for (int j = 0; j < 4; ++j) acc[i][j] = (floatx4){0.f, 0.f, 0.f, 0.f};

#pragma unroll
  for (int h = 0; h < 4; ++h) {
    gld_lds16(ap[h], &As[0][(size_t)(tid + 512 * h) * 8]);
    gld_lds16(bp[h], &Bs[0][(size_t)(tid + 512 * h) * 8]);
  }

  int p = 0;
  for (int t = 0; t < NT; ++t) {
    const bf16* asF = &As[p][0];
    const bf16* bsF = &Bs[p][0];
    bf16* asN = &As[p ^ 1][0];
    bf16* bsN = &Bs[p ^ 1][0];
    const int kn = (t + 1) * 64;
    const bool stage = (t + 1 < NT);

    asm volatile("" ::: "memory");
    __builtin_amdgcn_s_barrier();
    if (stage) {
      gld_lds16(ap[0] + kn, asN + (size_t)tid * 8);
      gld_lds16(bp[0] + kn, bsN + (size_t)tid * 8);
      asm volatile("s_waitcnt vmcnt(2)" ::: "memory");
    } else {
      asm volatile("s_waitcnt vmcnt(0)" ::: "memory");
    }
    __builtin_amdgcn_s_barrier();
    asm volatile("" ::: "memory");

    GEMM_TILE_PHASES(stage)
    p ^= 1;
  }

#pragma unroll
  for (int j = 0; j < 4; ++j) {
    const int col = n0 + wn * 64 + j * 16 + l15;
    const float bov = bo[col];
#pragma unroll
    for (int i = 0; i < 8; ++i) {
#pragma unroll
      for (int r = 0; r < 4; ++r) {
        const int rl = wm * 128 + i * 16 + quad * 4 + r;
        const size_t o = (size_t)(m0 + rl) * DIM + col;
        y[o] = acc[i][j][r] + bov + x[o];
      }
    }
  }
}

// ---- in-place RMSNorm over rows of d_out ----
__global__ __launch_bounds__(256) void rmsnorm_kernel(
    float* __restrict__ y, const float* __restrict__ w) {
  const int row = blockIdx.x;
  const int tid = threadIdx.x;
  float* yr = y + (size_t)row * DIM;
  float4 v0 = ((const float4*)yr)[tid];
  float4 v1 = ((const float4*)yr)[tid + 256];
  float ss = v0.x * v0.x + v0.y * v0.y + v0.z * v0.z + v0.w * v0.w +
             v1.x * v1.x + v1.y * v1.y + v1.z * v1.z + v1.w * v1.w;
#pragma unroll
  for (int off = 32; off > 0; off >>= 1) ss += __shfl_down(ss, off, 64);
  __shared__ float s4[4];
  const int lane = tid & 63, wid = tid >> 6;
  if (lane == 0) s4[wid] = ss;
  __syncthreads();
  const float tot = s4[0] + s4[1] + s4[2] + s4[3];
  const float r = rsqrtf(tot / (float)DIM + 1e-6f);
  float4 w0 = ((const float4*)w)[tid];
  float4 w1 = ((const float4*)w)[tid + 256];
  float4 o0 = make_float4(v0.x * r * w0.x, v0.y * r * w0.y, v0.z * r * w0.z, v0.w * r * w0.w);
  float4 o1 = make_float4(v1.x * r * w1.x, v1.y * r * w1.y, v1.z * r * w1.z, v1.w * r * w1.w);
  ((float4*)yr)[tid] = o0;
  ((float4*)yr)[tid + 256] = o1;
}

extern "C" void kernel_launch(void* const* d_in, const int* in_sizes, int n_in,
                              void* d_out, int out_size, void* d_ws, size_t ws_size,
                              hipStream_t stream) {
  const float* x  = (const float*)d_in[0];
  const float* Wr = (const float*)d_in[1];
  const float* br = (const float*)d_in[2];
  const float* We = (const float*)d_in[3];
  const float* be = (const float*)d_in[4];
  const float* Wo = (const float*)d_in[5];
  const float* bo = (const float*)d_in[6];
  const float* nw = (const float*)d_in[7];
  float* out = (float*)d_out;

  uint8_t* ws = (uint8_t*)d_ws;
  size_t off = 0;
  auto carve = [&](size_t bytes) -> void* {
    void* p = ws + off;
    off += (bytes + 255) & ~(size_t)255;
    return p;
  };
  int*   cnt       = (int*)carve(NE * sizeof(int));
  int*   aid_list  = (int*)carve((size_t)NE * T_TOK * sizeof(int));
  float* gate_list = (float*)carve((size_t)NE * T_TOK * sizeof(float));
  int2*  chunks    = (int2*)carve(MAX_CHUNKS * sizeof(int2));
  int*   nchunks   = (int*)carve(sizeof(int));
  bf16*  We_t      = (bf16*)carve((size_t)NE * DIM * DIM * sizeof(bf16));
  bf16*  Wo_t      = (bf16*)carve((size_t)DIM * DIM * sizeof(bf16));
  bf16*  aoutb     = (bf16*)carve((size_t)T_TOK * 2 * DIM * sizeof(bf16));
  bf16*  xb        = (bf16*)carve((size_t)T_TOK * DIM * sizeof(bf16));
  // hcomb aliases We_t: dead after expert_gemm; combine/proj run strictly later.
  bf16*  hcomb     = We_t;
  (void)ws_size; (void)in_sizes; (void)n_in; (void)out_size;

  hipMemsetAsync(cnt, 0, NE * sizeof(int), stream);
  transpose_convert<<<dim3(DIM / 32, DIM / 32, NE), 256, 0, stream>>>(We, We_t);
  transpose_convert<<<dim3(DIM / 32, DIM / 32, 1), 256, 0, stream>>>(Wo, Wo_t);
  router_kernel<<<T_TOK, 256, 0, stream>>>(x, Wr, br, cnt, aid_list, gate_list, xb);
  build_chunks<<<1, 64, 0, stream>>>(cnt, chunks, nchunks);
  expert_gemm<<<dim3(MAX_CHUNKS * 8), 512, 0, stream>>>(
      xb, We_t, be, cnt, aid_list, gate_list, chunks, nchunks, aoutb);
  combine_kernel<<<(T_TOK * DIM / 8) / 256, 256, 0, stream>>>(aoutb, hcomb);
  proj_gemm<<<dim3(PROJ_CIDS * 8), 512, 0, stream>>>(hcomb, Wo_t, bo, x, out);
  rmsnorm_kernel<<<T_TOK, 256, 0, stream>>>(out, nw);
}

// Round 2
// 863.779 us; speedup vs baseline: 1.0311x; 1.0311x over previous
//
#include <hip/hip_runtime.h>
#include <hip/hip_bf16.h>
#include <stdint.h>

typedef __bf16 bf16;
typedef __bf16 bf16x4 __attribute__((ext_vector_type(4)));
typedef __bf16 bf16x8 __attribute__((ext_vector_type(8)));
typedef float floatx4 __attribute__((ext_vector_type(4)));

#define T_TOK 8192
#define DIM 2048
#define NE 8
#define BM 128
#define BN 128
#define BK 32
#define NTIL (DIM / BK)   // 64 K-tiles
#define MAX_CHUNKS 136    // sum ceil(ne/128) <= 128+8

// ---- async global->LDS 16B. Per-lane global address free; LDS dest is
//      wave-uniform base + lane*16 (our layout is linear in tid). ----
__device__ inline void gld_lds16(const bf16* g, bf16* l) {
  __builtin_amdgcn_global_load_lds(
      (const __attribute__((address_space(1))) uint32_t*)g,
      (__attribute__((address_space(3))) uint32_t*)l, 16, 0, 0);
}

// ---- transpose [Dk,Dn] fp32 -> [Dn,Dk] bf16, batched over blockIdx.z ----
__global__ __launch_bounds__(256) void transpose_convert(
    const float* __restrict__ in, bf16* __restrict__ out) {
  __shared__ float tile[32][33];
  const int tx = threadIdx.x & 31;
  const int ty = threadIdx.x >> 5;
  const int n0 = blockIdx.x * 32;
  const int k0 = blockIdx.y * 32;
  const size_t base = (size_t)blockIdx.z * DIM * DIM;
  const float* src = in + base;
  bf16* dst = out + base;
#pragma unroll
  for (int i = 0; i < 32; i += 8)
    tile[ty + i][tx] = src[(size_t)(k0 + ty + i) * DIM + n0 + tx];
  __syncthreads();
#pragma unroll
  for (int i = 0; i < 32; i += 8)
    dst[(size_t)(n0 + ty + i) * DIM + k0 + tx] = (bf16)tile[tx][ty + i];
}

// ---- router (fused x->bf16): logits, top-2 (strict >, lower idx wins ties),
//      softmax gates, scatter (assign_id, gate) into per-expert lists ----
__global__ __launch_bounds__(256) void router_kernel(
    const float* __restrict__ x, const float* __restrict__ Wr,
    const float* __restrict__ br, int* __restrict__ cnt,
    int* __restrict__ aid_list, float* __restrict__ gate_list,
    bf16* __restrict__ xb) {
  const int t = blockIdx.x;
  const int tid = threadIdx.x;
  const float* xr = x + (size_t)t * DIM;
  bf16* xbr = xb + (size_t)t * DIM;
  float acc[8];
#pragma unroll
  for (int e = 0; e < 8; ++e) acc[e] = 0.f;
#pragma unroll
  for (int h = 0; h < 2; ++h) {
    const int d0 = tid * 4 + h * 1024;
    float4 xv = *(const float4*)&xr[d0];
    bf16x4 xc;
    xc[0] = (bf16)xv.x; xc[1] = (bf16)xv.y; xc[2] = (bf16)xv.z; xc[3] = (bf16)xv.w;
    *(bf16x4*)&xbr[d0] = xc;
    const float* wp = &Wr[(size_t)d0 * NE];
    float xe[4] = {xv.x, xv.y, xv.z, xv.w};
#pragma unroll
    for (int q = 0; q < 4; ++q) {
      float4 w0 = *(const float4*)&wp[q * 8];
      float4 w1 = *(const float4*)&wp[q * 8 + 4];
      acc[0] += xe[q] * w0.x; acc[1] += xe[q] * w0.y;
      acc[2] += xe[q] * w0.z; acc[3] += xe[q] * w0.w;
      acc[4] += xe[q] * w1.x; acc[5] += xe[q] * w1.y;
      acc[6] += xe[q] * w1.z; acc[7] += xe[q] * w1.w;
    }
  }
#pragma unroll
  for (int e = 0; e < 8; ++e) {
#pragma unroll
    for (int off = 32; off > 0; off >>= 1) acc[e] += __shfl_down(acc[e], off, 64);
  }
  __shared__ float red[4][8];
  const int lane = tid & 63, wid = tid >> 6;
  if (lane == 0) {
#pragma unroll
    for (int e = 0; e < 8; ++e) red[wid][e] = acc[e];
  }
  __syncthreads();
  if (tid == 0) {
    float lg[8];
#pragma unroll
    for (int e = 0; e < 8; ++e)
      lg[e] = red[0][e] + red[1][e] + red[2][e] + red[3][e] + br[e];
    int i0 = 0;
#pragma unroll
    for (int e = 1; e < 8; ++e) if (lg[e] > lg[i0]) i0 = e;
    int i1 = (i0 == 0) ? 1 : 0;
#pragma unroll
    for (int e = 0; e < 8; ++e)
      if (e != i0 && lg[e] > lg[i1]) i1 = e;
    const float g0 = 1.f / (1.f + expf(lg[i1] - lg[i0]));
    const float g1 = 1.f - g0;
    int p0 = atomicAdd(&cnt[i0], 1);
    aid_list[i0 * T_TOK + p0] = t * 2;
    gate_list[i0 * T_TOK + p0] = g0;
    int p1 = atomicAdd(&cnt[i1], 1);
    aid_list[i1 * T_TOK + p1] = t * 2 + 1;
    gate_list[i1 * T_TOK + p1] = g1;
  }
}

// ---- build compact (expert, m0) chunk table (128-row chunks) ----
__global__ void build_chunks(const int* __restrict__ cnt, int2* __restrict__ chunks,
                             int* __restrict__ nchunks) {
  if (threadIdx.x == 0 && blockIdx.x == 0) {
    int tot = 0;
#pragma unroll
    for (int e = 0; e < NE; ++e) {
      const int ne = cnt[e];
      for (int m0 = 0; m0 < ne; m0 += BM) chunks[tot++] = make_int2(e, m0);
    }
    *nchunks = tot;
  }
}

// ===========================================================================
// 128x128 tile, BK=32, 256 threads (2x2 waves, 64x64 per wave), double-
// buffered LDS (33 KB -> 4 blocks/CU via __launch_bounds__(256,4)).
// Guide T3-minimum schedule: STAGE(next) issued FIRST, then ds_read+MFMA,
// then ONE vmcnt(0)[+lgkmcnt] + raw s_barrier per K-tile. Cross-block TLP
// (4 blocks/CU) covers the per-tile drain.
//
// LDS tile [128 rows][32 k] bf16: row r = 64B; 4 chunks of 16B; chunk q of
// row r stored at position q^((r>>1)&3). Per 16-lane phase group of a
// ds_read_b128 this is 2-way bank aliasing = free (m136). Staged via
// linear-dest global_load_lds with pre-swizzled global k offset:
//   thread tid, pass h: row r=(tid>>2)+64h, pos c=tid&3, global chunk
//   q = c ^ ((tid>>3)&3) (h-independent since 64h ≡ 0 mod 4 after >>1).
// Fragment read (row R, k-step quad): pos = quad ^ ((R>>1)&3); since
// R = (multiple of 16) + l15, pos = quad ^ ((l15>>1)&3) for every frag.
// ===========================================================================

// ---- grouped expert GEMM: H = silu(Xg @ We[e]^T-layout + be[e]) * gate ----
__global__ __launch_bounds__(256, 4) void expert_gemm(
    const bf16* __restrict__ xb, const bf16* __restrict__ Wt,
    const float* __restrict__ be, const int* __restrict__ cnt,
    const int* __restrict__ aid_list, const float* __restrict__ gate_list,
    const int2* __restrict__ chunks, const int* __restrict__ nchunks,
    bf16* __restrict__ aout) {
  const int cid = blockIdx.x >> 4;
  if (cid >= *nchunks) return;
  const int2 ch = chunks[cid];
  const int e = ch.x;
  const int m0 = ch.y;
  const int ne = cnt[e];
  const int n0 = (blockIdx.x & 15) * BN;
  const int tid = threadIdx.x;

  __shared__ bf16 As[2][BM * BK];
  __shared__ bf16 Bs[2][BM * BK];
  __shared__ int aidS[BM];
  __shared__ float gateS[BM];

  if (tid < BM) {
    const int idx = m0 + tid;
    aidS[tid] = (idx < ne) ? aid_list[e * T_TOK + idx] : 0;
    gateS[tid] = (idx < ne) ? gate_list[e * T_TOK + idx] : 0.f;
  }
  __syncthreads();

  const int kq = ((tid & 3) ^ ((tid >> 3) & 3)) * 8;
  const int r0 = tid >> 2;
  const bf16* wb = Wt + (size_t)e * DIM * DIM;
  const bf16* ap[2];
  const bf16* bp[2];
#pragma unroll
  for (int h = 0; h < 2; ++h) {
    const int r = r0 + 64 * h;
    ap[h] = xb + (size_t)(aidS[r] >> 1) * DIM + kq;
    bp[h] = wb + (size_t)(n0 + r) * DIM + kq;
  }

  const int lane = tid & 63, w = tid >> 6;
  const int wm = w >> 1, wn = w & 1;
  const int quad = lane >> 4, l15 = lane & 15;
  const int xo = (quad ^ ((l15 >> 1) & 3)) * 8;
  int aoff[4], boff[4];
#pragma unroll
  for (int i = 0; i < 4; ++i) {
    aoff[i] = (wm * 64 + i * 16 + l15) * BK + xo;
    boff[i] = (wn * 64 + i * 16 + l15) * BK + xo;
  }

  floatx4 acc[4][4];
#pragma unroll
  for (int i = 0; i < 4; ++i)
#pragma unroll
    for (int j = 0; j < 4; ++j) acc[i][j] = (floatx4){0.f, 0.f, 0.f, 0.f};

  bf16* a_cur = &As[0][0]; bf16* a_nxt = &As[1][0];
  bf16* b_cur = &Bs[0][0]; bf16* b_nxt = &Bs[1][0];

  // prologue: stage tile 0
#pragma unroll
  for (int h = 0; h < 2; ++h) {
    gld_lds16(ap[h], a_cur + (tid + 256 * h) * 8);
    gld_lds16(bp[h], b_cur + (tid + 256 * h) * 8);
  }
  asm volatile("s_waitcnt vmcnt(0)" ::: "memory");
  __builtin_amdgcn_s_barrier();

  for (int t = 0; t < NTIL; ++t) {
    if (t + 1 < NTIL) {
      const int kn = (t + 1) * BK;
#pragma unroll
      for (int h = 0; h < 2; ++h) {
        gld_lds16(ap[h] + kn, a_nxt + (tid + 256 * h) * 8);
        gld_lds16(bp[h] + kn, b_nxt + (tid + 256 * h) * 8);
      }
    }
    bf16x8 af[4];
#pragma unroll
    for (int i = 0; i < 4; ++i) af[i] = *(const bf16x8*)&a_cur[aoff[i]];
#pragma unroll
    for (int j = 0; j < 4; ++j) {
      const bf16x8 bfr = *(const bf16x8*)&b_cur[boff[j]];
#pragma unroll
      for (int i = 0; i < 4; ++i)
        acc[i][j] = __builtin_amdgcn_mfma_f32_16x16x32_bf16(af[i], bfr, acc[i][j], 0, 0, 0);
    }
    asm volatile("s_waitcnt vmcnt(0)" ::: "memory");
    __builtin_amdgcn_s_barrier();
    bf16* tA = a_cur; a_cur = a_nxt; a_nxt = tA;
    bf16* tB = b_cur; b_cur = b_nxt; b_nxt = tB;
  }

  // epilogue: + be, silu, * gate, scatter bf16 to assignment row
#pragma unroll
  for (int j = 0; j < 4; ++j) {
    const int col = n0 + wn * 64 + j * 16 + l15;
    const float bev = be[e * DIM + col];
#pragma unroll
    for (int i = 0; i < 4; ++i) {
#pragma unroll
      for (int r = 0; r < 4; ++r) {
        const int rl = wm * 64 + i * 16 + quad * 4 + r;
        if (m0 + rl < ne) {
          float v = acc[i][j][r] + bev;
          v = v / (1.f + __expf(-v));
          v *= gateS[rl];
          aout[(size_t)aidS[rl] * DIM + col] = (bf16)v;
        }
      }
    }
  }
}

// ---- output projection with FUSED combine: A-rows = aout[2t] + aout[2t+1]
//      (reg-staged, T14 split: loads issued early, summed+ds_written after
//      the MFMA window), B = Wot via global_load_lds. y = A@Wo + bo + x. ----
__global__ __launch_bounds__(256, 4) void proj_gemm(
    const bf16* __restrict__ aout, const bf16* __restrict__ Wot,
    const float* __restrict__ bo, const float* __restrict__ x,
    float* __restrict__ y) {
  const int m0 = (int)(blockIdx.x >> 4) * BM;
  const int n0 = (int)(blockIdx.x & 15) * BN;
  const int tid = threadIdx.x;

  __shared__ bf16 As[2][BM * BK];
  __shared__ bf16 Bs[2][BM * BK];

  const int kq = ((tid & 3) ^ ((tid >> 3) & 3)) * 8;
  const int r0 = tid >> 2;
  const bf16* a0[2];
  const bf16* bp[2];
#pragma unroll
  for (int h = 0; h < 2; ++h) {
    const int r = r0 + 64 * h;
    a0[h] = aout + (size_t)(2 * (m0 + r)) * DIM + kq;  // slot0; slot1 at +DIM
    bp[h] = Wot + (size_t)(n0 + r) * DIM + kq;
  }

  const int lane = tid & 63, w = tid >> 6;
  const int wm = w >> 1, wn = w & 1;
  const int quad = lane >> 4, l15 = lane & 15;
  const int xo = (quad ^ ((l15 >> 1) & 3)) * 8;
  int aoff[4], boff[4];
#pragma unroll
  for (int i = 0; i < 4; ++i) {
    aoff[i] = (wm * 64 + i * 16 + l15) * BK + xo;
    boff[i] = (wn * 64 + i * 16 + l15) * BK + xo;
  }

  floatx4 acc[4][4];
#pragma unroll
  for (int i = 0; i < 4; ++i)
#pragma unroll
    for (int j = 0; j < 4; ++j) acc[i][j] = (floatx4){0.f, 0.f, 0.f, 0.f};

  bf16* a_cur = &As[0][0]; bf16* a_nxt = &As[1][0];
  bf16* b_cur = &Bs[0][0]; bf16* b_nxt = &Bs[1][0];

  // prologue: stage tile 0 (A reg-staged with combine)
  {
    bf16x8 u[2][2];
#pragma unroll
    for (int h = 0; h < 2; ++h) {
      gld_lds16(bp[h], b_cur + (tid + 256 * h) * 8);
      u[h][0] = *(const bf16x8*)(a0[h]);
      u[h][1] = *(const bf16x8*)(a0[h] + DIM);
    }
#pragma unroll
    for (int h = 0; h < 2; ++h) {
      bf16x8 s;
#pragma unroll
      for (int q = 0; q < 8; ++q)
        s[q] = (bf16)((float)u[h][0][q] + (float)u[h][1][q]);
      *(bf16x8*)&a_cur[(tid + 256 * h) * 8] = s;
    }
  }
  asm volatile("s_waitcnt vmcnt(0) lgkmcnt(0)" ::: "memory");
  __builtin_amdgcn_s_barrier();

  for (int t = 0; t < NTIL; ++t) {
    bf16x8 v[2][2];
    const bool stage = (t + 1 < NTIL);
    if (stage) {
      const int kn = (t + 1) * BK;
#pragma unroll
      for (int h = 0; h < 2; ++h) {
        gld_lds16(bp[h] + kn, b_nxt + (tid + 256 * h) * 8);
        v[h][0] = *(const bf16x8*)(a0[h] + kn);
        v[h][1] = *(const bf16x8*)(a0[h] + kn + DIM);
      }
    }
    bf16x8 af[4];
#pragma unroll
    for (int i = 0; i < 4; ++i) af[i] = *(const bf16x8*)&a_cur[aoff[i]];
#pragma unroll
    for (int j = 0; j < 4; ++j) {
      const bf16x8 bfr = *(const bf16x8*)&b_cur[boff[j]];
#pragma unroll
      for (int i = 0; i < 4; ++i)
        acc[i][j] = __builtin_amdgcn_mfma_f32_16x16x32_bf16(af[i], bfr, acc[i][j], 0, 0, 0);
    }
    if (stage) {
#pragma unroll
      for (int h = 0; h < 2; ++h) {
        bf16x8 s;
#pragma unroll
        for (int q = 0; q < 8; ++q)
          s[q] = (bf16)((float)v[h][0][q] + (float)v[h][1][q]);
        *(bf16x8*)&a_nxt[(tid + 256 * h) * 8] = s;
      }
    }
    asm volatile("s_waitcnt vmcnt(0) lgkmcnt(0)" ::: "memory");
    __builtin_amdgcn_s_barrier();
    bf16* tA = a_cur; a_cur = a_nxt; a_nxt = tA;
    bf16* tB = b_cur; b_cur = b_nxt; b_nxt = tB;
  }

  // epilogue: y = acc + bo + x (fp32)
#pragma unroll
  for (int j = 0; j < 4; ++j) {
    const int col = n0 + wn * 64 + j * 16 + l15;
    const float bov = bo[col];
#pragma unroll
    for (int i = 0; i < 4; ++i) {
#pragma unroll
      for (int r = 0; r < 4; ++r) {
        const int rl = wm * 64 + i * 16 + quad * 4 + r;
        const size_t o = (size_t)(m0 + rl) * DIM + col;
        y[o] = acc[i][j][r] + bov + x[o];
      }
    }
  }
}

// ---- in-place RMSNorm over rows of d_out ----
__global__ __launch_bounds__(256) void rmsnorm_kernel(
    float* __restrict__ y, const float* __restrict__ w) {
  const int row = blockIdx.x;
  const int tid = threadIdx.x;
  float* yr = y + (size_t)row * DIM;
  float4 v0 = ((const float4*)yr)[tid];
  float4 v1 = ((const float4*)yr)[tid + 256];
  float ss = v0.x * v0.x + v0.y * v0.y + v0.z * v0.z + v0.w * v0.w +
             v1.x * v1.x + v1.y * v1.y + v1.z * v1.z + v1.w * v1.w;
#pragma unroll
  for (int off = 32; off > 0; off >>= 1) ss += __shfl_down(ss, off, 64);
  __shared__ float s4[4];
  const int lane = tid & 63, wid = tid >> 6;
  if (lane == 0) s4[wid] = ss;
  __syncthreads();
  const float tot = s4[0] + s4[1] + s4[2] + s4[3];
  const float r = rsqrtf(tot / (float)DIM + 1e-6f);
  float4 w0 = ((const float4*)w)[tid];
  float4 w1 = ((const float4*)w)[tid + 256];
  float4 o0 = make_float4(v0.x * r * w0.x, v0.y * r * w0.y, v0.z * r * w0.z, v0.w * r * w0.w);
  float4 o1 = make_float4(v1.x * r * w1.x, v1.y * r * w1.y, v1.z * r * w1.z, v1.w * r * w1.w);
  ((float4*)yr)[tid] = o0;
  ((float4*)yr)[tid + 256] = o1;
}

extern "C" void kernel_launch(void* const* d_in, const int* in_sizes, int n_in,
                              void* d_out, int out_size, void* d_ws, size_t ws_size,
                              hipStream_t stream) {
  const float* x  = (const float*)d_in[0];
  const float* Wr = (const float*)d_in[1];
  const float* br = (const float*)d_in[2];
  const float* We = (const float*)d_in[3];
  const float* be = (const float*)d_in[4];
  const float* Wo = (const float*)d_in[5];
  const float* bo = (const float*)d_in[6];
  const float* nw = (const float*)d_in[7];
  float* out = (float*)d_out;

  uint8_t* ws = (uint8_t*)d_ws;
  size_t off = 0;
  auto carve = [&](size_t bytes) -> void* {
    void* p = ws + off;
    off += (bytes + 255) & ~(size_t)255;
    return p;
  };
  int*   cnt       = (int*)carve(NE * sizeof(int));
  int*   aid_list  = (int*)carve((size_t)NE * T_TOK * sizeof(int));
  float* gate_list = (float*)carve((size_t)NE * T_TOK * sizeof(float));
  int2*  chunks    = (int2*)carve(MAX_CHUNKS * sizeof(int2));
  int*   nchunks   = (int*)carve(sizeof(int));
  bf16*  We_t      = (bf16*)carve((size_t)NE * DIM * DIM * sizeof(bf16));
  bf16*  Wo_t      = (bf16*)carve((size_t)DIM * DIM * sizeof(bf16));
  bf16*  aoutb     = (bf16*)carve((size_t)T_TOK * 2 * DIM * sizeof(bf16));
  bf16*  xb        = (bf16*)carve((size_t)T_TOK * DIM * sizeof(bf16));
  (void)ws_size; (void)in_sizes; (void)n_in; (void)out_size;

  hipMemsetAsync(cnt, 0, NE * sizeof(int), stream);
  transpose_convert<<<dim3(DIM / 32, DIM / 32, NE), 256, 0, stream>>>(We, We_t);
  transpose_convert<<<dim3(DIM / 32, DIM / 32, 1), 256, 0, stream>>>(Wo, Wo_t);
  router_kernel<<<T_TOK, 256, 0, stream>>>(x, Wr, br, cnt, aid_list, gate_list, xb);
  build_chunks<<<1, 64, 0, stream>>>(cnt, chunks, nchunks);
  expert_gemm<<<dim3(MAX_CHUNKS * 16), 256, 0, stream>>>(
      xb, We_t, be, cnt, aid_list, gate_list, chunks, nchunks, aoutb);
  proj_gemm<<<dim3((T_TOK / BM) * 16), 256, 0, stream>>>(aoutb, Wo_t, bo, x, out);
  rmsnorm_kernel<<<T_TOK, 256, 0, stream>>>(out, nw);
}

// Round 3
// 853.829 us; speedup vs baseline: 1.0431x; 1.0117x over previous
//
#include <hip/hip_runtime.h>
#include <hip/hip_bf16.h>
#include <stdint.h>

typedef __bf16 bf16;
typedef __bf16 bf16x4 __attribute__((ext_vector_type(4)));
typedef __bf16 bf16x8 __attribute__((ext_vector_type(8)));
typedef float floatx4 __attribute__((ext_vector_type(4)));

#define T_TOK 8192
#define DIM 2048
#define NE 8
#define EPAD 2560        // per-expert row capacity: mean 2048, sigma ~42 (binomial) -> +12 sigma margin
#define MAX_CHUNKS 136   // sum ceil(ne/128) <= 128 + 8

// ---- async global->LDS 16B. Per-lane global address free; LDS dest is
//      wave-uniform base + lane*16 (our layout is linear in tid). ----
__device__ inline void gld_lds16(const bf16* g, bf16* l) {
  __builtin_amdgcn_global_load_lds(
      (const __attribute__((address_space(1))) uint32_t*)g,
      (__attribute__((address_space(3))) uint32_t*)l, 16, 0, 0);
}

// ---- transpose [Dk,Dn] fp32 -> [Dn,Dk] bf16. z<8: We[z]; z==8: Wo.
//      One lane of the z==8 (0,0) block also zeroes cnt (replaces memset;
//      runs strictly before router in-stream). ----
__global__ __launch_bounds__(256) void transpose_convert(
    const float* __restrict__ We, const float* __restrict__ Wo,
    bf16* __restrict__ We_t, bf16* __restrict__ Wo_t, int* __restrict__ cnt) {
  const int z = blockIdx.z;
  if (z == 8 && blockIdx.x == 0 && blockIdx.y == 0 && threadIdx.x < NE)
    cnt[threadIdx.x] = 0;
  const float* src = (z < 8) ? We + (size_t)z * DIM * DIM : Wo;
  bf16* dst = (z < 8) ? We_t + (size_t)z * DIM * DIM : Wo_t;
  __shared__ float tile[32][33];
  const int tx = threadIdx.x & 31;
  const int ty = threadIdx.x >> 5;
  const int n0 = blockIdx.x * 32;
  const int k0 = blockIdx.y * 32;
#pragma unroll
  for (int i = 0; i < 32; i += 8)
    tile[ty + i][tx] = src[(size_t)(k0 + ty + i) * DIM + n0 + tx];
  __syncthreads();
#pragma unroll
  for (int i = 0; i < 32; i += 8)
    dst[(size_t)(n0 + ty + i) * DIM + k0 + tx] = (bf16)tile[tx][ty + i];
}

// ---- router: logits, top-2 (strict >, lower idx wins ties), softmax gates.
//      GATHERING router: the whole block writes its token row (bf16) directly
//      into the dense per-expert buffers xg[e][p] for both selected experts,
//      so expert_gemm stages a fully dense A. Also records inv[t] = the two
//      dense row ids for proj's fused combine. ----
__global__ __launch_bounds__(256) void router_kernel(
    const float* __restrict__ x, const float* __restrict__ Wr,
    const float* __restrict__ br, int* __restrict__ cnt,
    float* __restrict__ gate_list, int2* __restrict__ inv,
    bf16* __restrict__ xg) {
  const int t = blockIdx.x;
  const int tid = threadIdx.x;
  const float* xr = x + (size_t)t * DIM;
  float4 xv[2];
  float acc[8];
#pragma unroll
  for (int e = 0; e < 8; ++e) acc[e] = 0.f;
#pragma unroll
  for (int h = 0; h < 2; ++h) {
    const int d0 = tid * 4 + h * 1024;
    xv[h] = *(const float4*)&xr[d0];
    const float* wp = &Wr[(size_t)d0 * NE];
    float xe[4] = {xv[h].x, xv[h].y, xv[h].z, xv[h].w};
#pragma unroll
    for (int q = 0; q < 4; ++q) {
      float4 w0 = *(const float4*)&wp[q * 8];
      float4 w1 = *(const float4*)&wp[q * 8 + 4];
      acc[0] += xe[q] * w0.x; acc[1] += xe[q] * w0.y;
      acc[2] += xe[q] * w0.z; acc[3] += xe[q] * w0.w;
      acc[4] += xe[q] * w1.x; acc[5] += xe[q] * w1.y;
      acc[6] += xe[q] * w1.z; acc[7] += xe[q] * w1.w;
    }
  }
#pragma unroll
  for (int e = 0; e < 8; ++e) {
#pragma unroll
    for (int off = 32; off > 0; off >>= 1) acc[e] += __shfl_down(acc[e], off, 64);
  }
  __shared__ float red[4][8];
  __shared__ int sRow[2];
  const int lane = tid & 63, wid = tid >> 6;
  if (lane == 0) {
#pragma unroll
    for (int e = 0; e < 8; ++e) red[wid][e] = acc[e];
  }
  __syncthreads();
  if (tid == 0) {
    float lg[8];
#pragma unroll
    for (int e = 0; e < 8; ++e)
      lg[e] = red[0][e] + red[1][e] + red[2][e] + red[3][e] + br[e];
    int i0 = 0;
#pragma unroll
    for (int e = 1; e < 8; ++e) if (lg[e] > lg[i0]) i0 = e;
    int i1 = (i0 == 0) ? 1 : 0;
#pragma unroll
    for (int e = 0; e < 8; ++e)
      if (e != i0 && lg[e] > lg[i1]) i1 = e;
    const float g0 = 1.f / (1.f + expf(lg[i1] - lg[i0]));
    const float g1 = 1.f - g0;
    const int p0 = atomicAdd(&cnt[i0], 1);
    const int p1 = atomicAdd(&cnt[i1], 1);
    gate_list[i0 * T_TOK + p0] = g0;
    gate_list[i1 * T_TOK + p1] = g1;
    sRow[0] = i0 * EPAD + p0;
    sRow[1] = i1 * EPAD + p1;
    inv[t] = make_int2(sRow[0], sRow[1]);
  }
  __syncthreads();
  const size_t r0 = (size_t)sRow[0] * DIM;
  const size_t r1 = (size_t)sRow[1] * DIM;
#pragma unroll
  for (int h = 0; h < 2; ++h) {
    const int d0 = tid * 4 + h * 1024;
    bf16x4 xc;
    xc[0] = (bf16)xv[h].x; xc[1] = (bf16)xv[h].y;
    xc[2] = (bf16)xv[h].z; xc[3] = (bf16)xv[h].w;
    *(bf16x4*)&xg[r0 + d0] = xc;
    *(bf16x4*)&xg[r1 + d0] = xc;
  }
}

// ===========================================================================
// Proven round-0 GEMM core: 128x128 tile, BK=64, 256 threads (2x2 waves,
// 64x64/wave), single-buffered LDS, {stage -> sync -> 2x16 MFMA -> sync}.
// LDS tile [128 rows][64 k] bf16 in 16B chunks, XOR swizzle: row r, k-block
// kb stored at position kb^(r&7); staged with pre-swizzled global k offset.
// Fragment read (row, kb): offset = row*64 + ((kb^(row&7))*8). Conflict-free
// (measured 0 in r0/r2).
// ===========================================================================

// ---- grouped expert GEMM, DENSE A: H = silu(xg[e] @ We[e]^T + be[e])*gate,
//      dense output aoutc[e][p]. Chunk resolved per-block from cnt (8-step
//      scan) -- no build_chunks kernel. ----
__global__ __launch_bounds__(256, 3) void expert_gemm(
    const bf16* __restrict__ xg, const bf16* __restrict__ Wt,
    const float* __restrict__ be, const int* __restrict__ cnt,
    const float* __restrict__ gate_list, bf16* __restrict__ aoutc) {
  const int cid = blockIdx.x;
  int e = -1, m0 = 0;
  {
    int acc = 0;
#pragma unroll
    for (int q = 0; q < NE; ++q) {
      const int c = (cnt[q] + 127) >> 7;
      if (e < 0 && cid < acc + c) { e = q; m0 = (cid - acc) * 128; }
      acc += c;
    }
  }
  if (e < 0) return;
  const int ne = cnt[e];
  const int n0 = blockIdx.y * 128;
  const int tid = threadIdx.x;

  __shared__ bf16 As[128 * 64];
  __shared__ bf16 Bs[128 * 64];
  __shared__ float gateS[128];

  if (tid < 128)
    gateS[tid] = (m0 + tid < ne) ? gate_list[e * T_TOK + m0 + tid] : 0.f;

  const int r0 = tid >> 3;
  const int kq = ((tid & 7) ^ (r0 & 7)) * 8;
  const bf16* wbase = Wt + (size_t)e * DIM * DIM;
  const bf16* abase = xg + (size_t)(e * EPAD + m0) * DIM;
  const bf16* ap[4];
  const bf16* bp[4];
#pragma unroll
  for (int h = 0; h < 4; ++h) {
    const int r = r0 + 32 * h;
    ap[h] = abase + (size_t)r * DIM + kq;   // rows >= ne read garbage; their
    bp[h] = wbase + (size_t)(n0 + r) * DIM + kq;  // output rows are masked off
  }
  bf16* const asF = As;
  bf16* const bsF = Bs;

  const int lane = tid & 63, w = tid >> 6;
  const int wr = (w >> 1) * 64, wc = (w & 1) * 64;
  const int quad = lane >> 4, l15 = lane & 15;

  floatx4 acc[4][4];
#pragma unroll
  for (int i = 0; i < 4; ++i)
#pragma unroll
    for (int j = 0; j < 4; ++j) acc[i][j] = (floatx4){0.f, 0.f, 0.f, 0.f};

  int aoff[2][4], boff[2][4];
#pragma unroll
  for (int s = 0; s < 2; ++s) {
    const int kb = s * 4 + quad;
#pragma unroll
    for (int i = 0; i < 4; ++i) {
      const int mi = wr + i * 16 + l15;
      aoff[s][i] = mi * 64 + ((kb ^ (mi & 7)) * 8);
      const int nj = wc + i * 16 + l15;
      boff[s][i] = nj * 64 + ((kb ^ (nj & 7)) * 8);
    }
  }

  for (int k0 = 0; k0 < DIM; k0 += 64) {
#pragma unroll
    for (int h = 0; h < 4; ++h) {
      gld_lds16(bp[h] + k0, bsF + ((size_t)tid + 256 * h) * 8);
      gld_lds16(ap[h] + k0, asF + ((size_t)tid + 256 * h) * 8);
    }
    __syncthreads();
#pragma unroll
    for (int s = 0; s < 2; ++s) {
      bf16x8 af[4], bfr[4];
#pragma unroll
      for (int i = 0; i < 4; ++i) af[i] = *(const bf16x8*)&asF[aoff[s][i]];
#pragma unroll
      for (int j = 0; j < 4; ++j) bfr[j] = *(const bf16x8*)&bsF[boff[s][j]];
#pragma unroll
      for (int i = 0; i < 4; ++i)
#pragma unroll
        for (int j = 0; j < 4; ++j)
          acc[i][j] = __builtin_amdgcn_mfma_f32_16x16x32_bf16(af[i], bfr[j], acc[i][j], 0, 0, 0);
    }
    __syncthreads();
  }

  // epilogue: + be, silu, * gate, DENSE store to aoutc[e*EPAD + m0 + rl]
#pragma unroll
  for (int j = 0; j < 4; ++j) {
    const int col = n0 + wc + j * 16 + l15;
    const float bev = be[e * DIM + col];
#pragma unroll
    for (int i = 0; i < 4; ++i) {
#pragma unroll
      for (int r = 0; r < 4; ++r) {
        const int rl = wr + i * 16 + quad * 4 + r;
        if (m0 + rl < ne) {
          float v = acc[i][j][r] + bev;
          v = v / (1.f + __expf(-v));
          v *= gateS[rl];
          aoutc[(size_t)(e * EPAD + m0 + rl) * DIM + col] = (bf16)v;
        }
      }
    }
  }
}

// ---- output projection with FUSED combine: A-row(t) = aoutc[inv[t].x] +
//      aoutc[inv[t].y] (gates pre-applied in expert), reg-staged to LDS;
//      B = Wot via global_load_lds. y = A@Wo + bo + x. ----
__global__ __launch_bounds__(256, 3) void proj_gemm(
    const bf16* __restrict__ aoutc, const bf16* __restrict__ Wot,
    const int2* __restrict__ inv, const float* __restrict__ bo,
    const float* __restrict__ x, float* __restrict__ y) {
  const int m0 = blockIdx.x * 128;
  const int n0 = blockIdx.y * 128;
  const int tid = threadIdx.x;

  __shared__ bf16 As[128 * 64];
  __shared__ bf16 Bs[128 * 64];

  const int r0 = tid >> 3;
  const int kq = ((tid & 7) ^ (r0 & 7)) * 8;
  const bf16* a0[4];
  const bf16* a1[4];
  const bf16* bp[4];
#pragma unroll
  for (int h = 0; h < 4; ++h) {
    const int r = r0 + 32 * h;
    const int2 iv = inv[m0 + r];
    a0[h] = aoutc + (size_t)iv.x * DIM + kq;
    a1[h] = aoutc + (size_t)iv.y * DIM + kq;
    bp[h] = Wot + (size_t)(n0 + r) * DIM + kq;
  }
  bf16* const asF = As;
  bf16* const bsF = Bs;

  const int lane = tid & 63, w = tid >> 6;
  const int wr = (w >> 1) * 64, wc = (w & 1) * 64;
  const int quad = lane >> 4, l15 = lane & 15;

  floatx4 acc[4][4];
#pragma unroll
  for (int i = 0; i < 4; ++i)
#pragma unroll
    for (int j = 0; j < 4; ++j) acc[i][j] = (floatx4){0.f, 0.f, 0.f, 0.f};

  int aoff[2][4], boff[2][4];
#pragma unroll
  for (int s = 0; s < 2; ++s) {
    const int kb = s * 4 + quad;
#pragma unroll
    for (int i = 0; i < 4; ++i) {
      const int mi = wr + i * 16 + l15;
      aoff[s][i] = mi * 64 + ((kb ^ (mi & 7)) * 8);
      const int nj = wc + i * 16 + l15;
      boff[s][i] = nj * 64 + ((kb ^ (nj & 7)) * 8);
    }
  }

  for (int k0 = 0; k0 < DIM; k0 += 64) {
#pragma unroll
    for (int h = 0; h < 4; ++h)
      gld_lds16(bp[h] + k0, bsF + ((size_t)tid + 256 * h) * 8);
    bf16x8 u0[4], u1[4];
#pragma unroll
    for (int h = 0; h < 4; ++h) {
      u0[h] = *(const bf16x8*)(a0[h] + k0);
      u1[h] = *(const bf16x8*)(a1[h] + k0);
    }
#pragma unroll
    for (int h = 0; h < 4; ++h) {
      bf16x8 s;
#pragma unroll
      for (int q = 0; q < 8; ++q)
        s[q] = (bf16)((float)u0[h][q] + (float)u1[h][q]);
      *(bf16x8*)&asF[((size_t)tid + 256 * h) * 8] = s;
    }
    __syncthreads();
#pragma unroll
    for (int s = 0; s < 2; ++s) {
      bf16x8 af[4], bfr[4];
#pragma unroll
      for (int i = 0; i < 4; ++i) af[i] = *(const bf16x8*)&asF[aoff[s][i]];
#pragma unroll
      for (int j = 0; j < 4; ++j) bfr[j] = *(const bf16x8*)&bsF[boff[s][j]];
#pragma unroll
      for (int i = 0; i < 4; ++i)
#pragma unroll
        for (int j = 0; j < 4; ++j)
          acc[i][j] = __builtin_amdgcn_mfma_f32_16x16x32_bf16(af[i], bfr[j], acc[i][j], 0, 0, 0);
    }
    __syncthreads();
  }

  // epilogue: y = acc + bo + x (fp32)
#pragma unroll
  for (int j = 0; j < 4; ++j) {
    const int col = n0 + wc + j * 16 + l15;
    const float bov = bo[col];
#pragma unroll
    for (int i = 0; i < 4; ++i) {
#pragma unroll
      for (int r = 0; r < 4; ++r) {
        const int rl = wr + i * 16 + quad * 4 + r;
        const size_t o = (size_t)(m0 + rl) * DIM + col;
        y[o] = acc[i][j][r] + bov + x[o];
      }
    }
  }
}

// ---- in-place RMSNorm over rows of d_out ----
__global__ __launch_bounds__(256) void rmsnorm_kernel(
    float* __restrict__ y, const float* __restrict__ w) {
  const int row = blockIdx.x;
  const int tid = threadIdx.x;
  float* yr = y + (size_t)row * DIM;
  float4 v0 = ((const float4*)yr)[tid];
  float4 v1 = ((const float4*)yr)[tid + 256];
  float ss = v0.x * v0.x + v0.y * v0.y + v0.z * v0.z + v0.w * v0.w +
             v1.x * v1.x + v1.y * v1.y + v1.z * v1.z + v1.w * v1.w;
#pragma unroll
  for (int off = 32; off > 0; off >>= 1) ss += __shfl_down(ss, off, 64);
  __shared__ float s4[4];
  const int lane = tid & 63, wid = tid >> 6;
  if (lane == 0) s4[wid] = ss;
  __syncthreads();
  const float tot = s4[0] + s4[1] + s4[2] + s4[3];
  const float r = rsqrtf(tot / (float)DIM + 1e-6f);
  float4 w0 = ((const float4*)w)[tid];
  float4 w1 = ((const float4*)w)[tid + 256];
  float4 o0 = make_float4(v0.x * r * w0.x, v0.y * r * w0.y, v0.z * r * w0.z, v0.w * r * w0.w);
  float4 o1 = make_float4(v1.x * r * w1.x, v1.y * r * w1.y, v1.z * r * w1.z, v1.w * r * w1.w);
  ((float4*)yr)[tid] = o0;
  ((float4*)yr)[tid + 256] = o1;
}

extern "C" void kernel_launch(void* const* d_in, const int* in_sizes, int n_in,
                              void* d_out, int out_size, void* d_ws, size_t ws_size,
                              hipStream_t stream) {
  const float* x  = (const float*)d_in[0];
  const float* Wr = (const float*)d_in[1];
  const float* br = (const float*)d_in[2];
  const float* We = (const float*)d_in[3];
  const float* be = (const float*)d_in[4];
  const float* Wo = (const float*)d_in[5];
  const float* bo = (const float*)d_in[6];
  const float* nw = (const float*)d_in[7];
  float* out = (float*)d_out;

  uint8_t* ws = (uint8_t*)d_ws;
  size_t off = 0;
  auto carve = [&](size_t bytes) -> void* {
    void* p = ws + off;
    off += (bytes + 255) & ~(size_t)255;
    return p;
  };
  int*   cnt       = (int*)carve(NE * sizeof(int));
  float* gate_list = (float*)carve((size_t)NE * T_TOK * sizeof(float));
  int2*  inv       = (int2*)carve((size_t)T_TOK * sizeof(int2));
  bf16*  We_t      = (bf16*)carve((size_t)NE * DIM * DIM * sizeof(bf16));
  bf16*  Wo_t      = (bf16*)carve((size_t)DIM * DIM * sizeof(bf16));
  bf16*  xg        = (bf16*)carve((size_t)NE * EPAD * DIM * sizeof(bf16));
  bf16*  aoutc     = (bf16*)carve((size_t)NE * EPAD * DIM * sizeof(bf16));
  (void)ws_size; (void)in_sizes; (void)n_in; (void)out_size;

  // 5 launches (was 9): memset folded into transpose; We/Wo transposes merged;
  // build_chunks inlined into expert_gemm; combine fused into proj_gemm.
  transpose_convert<<<dim3(DIM / 32, DIM / 32, NE + 1), 256, 0, stream>>>(
      We, Wo, We_t, Wo_t, cnt);
  router_kernel<<<T_TOK, 256, 0, stream>>>(x, Wr, br, cnt, gate_list, inv, xg);
  expert_gemm<<<dim3(MAX_CHUNKS, DIM / 128), 256, 0, stream>>>(
      xg, We_t, be, cnt, gate_list, aoutc);
  proj_gemm<<<dim3(T_TOK / 128, DIM / 128), 256, 0, stream>>>(
      aoutc, Wo_t, inv, bo, x, out);
  rmsnorm_kernel<<<T_TOK, 256, 0, stream>>>(out, nw);
}

// Round 4
// 842.082 us; speedup vs baseline: 1.0577x; 1.0140x over previous
//
#include <hip/hip_runtime.h>
#include <hip/hip_bf16.h>
#include <stdint.h>

typedef __bf16 bf16;
typedef __bf16 bf16x4 __attribute__((ext_vector_type(4)));
typedef __bf16 bf16x8 __attribute__((ext_vector_type(8)));
typedef float floatx4 __attribute__((ext_vector_type(4)));

#define T_TOK 8192
#define DIM 2048
#define NE 8
#define EPAD 2560        // per-expert row capacity (multiple of 256)
#define NTIL (DIM / 64)  // 32 K-tiles of BK=64
#define MAXC 72          // sum ceil(ne/256) <= 16384/256 + 8 = 72 ALWAYS

// ---- async global->LDS 16B. Per-lane global address free; LDS dest is
//      wave-uniform base + lane*16 (our layout is linear in tid). ----
__device__ inline void gld_lds16(const bf16* g, bf16* l) {
  __builtin_amdgcn_global_load_lds(
      (const __attribute__((address_space(1))) uint32_t*)g,
      (__attribute__((address_space(3))) uint32_t*)l, 16, 0, 0);
}

// ---- transpose [Dk,Dn] fp32 -> [Dn,Dk] bf16, 64x64 tiles. z<8: We[z];
//      z==8: Wo. One z==8 block also zeroes cnt (runs before router). ----
__global__ __launch_bounds__(256) void transpose_convert(
    const float* __restrict__ We, const float* __restrict__ Wo,
    bf16* __restrict__ We_t, bf16* __restrict__ Wo_t, int* __restrict__ cnt) {
  const int z = blockIdx.z;
  if (z == 8 && blockIdx.x == 0 && blockIdx.y == 0 && threadIdx.x < NE)
    cnt[threadIdx.x] = 0;
  const float* src = (z < 8) ? We + (size_t)z * DIM * DIM : Wo;
  bf16* dst = (z < 8) ? We_t + (size_t)z * DIM * DIM : Wo_t;
  __shared__ float tile[64][65];
  const int tx = threadIdx.x & 63, ty = threadIdx.x >> 6;
  const int n0 = blockIdx.x * 64, k0 = blockIdx.y * 64;
#pragma unroll
  for (int i = 0; i < 16; ++i)
    tile[ty + 4 * i][tx] = src[(size_t)(k0 + ty + 4 * i) * DIM + n0 + tx];
  __syncthreads();
  const int kc = (threadIdx.x & 15) * 4;
  const int nrb = threadIdx.x >> 4;
#pragma unroll
  for (int p = 0; p < 4; ++p) {
    const int nr = nrb + 16 * p;
    bf16x4 v;
#pragma unroll
    for (int q = 0; q < 4; ++q) v[q] = (bf16)tile[kc + q][nr];
    *(bf16x4*)&dst[(size_t)(n0 + nr) * DIM + k0 + kc] = v;
  }
}

// ---- router: logits, top-2 (strict >, lower idx wins ties), softmax gates.
//      Writes token row (bf16) into dense per-expert buffers xg[e][p] for
//      both selected experts; records inv[t] = the two dense row ids. ----
__global__ __launch_bounds__(256) void router_kernel(
    const float* __restrict__ x, const float* __restrict__ Wr,
    const float* __restrict__ br, int* __restrict__ cnt,
    float* __restrict__ gate_list, int2* __restrict__ inv,
    bf16* __restrict__ xg) {
  const int t = blockIdx.x;
  const int tid = threadIdx.x;
  const float* xr = x + (size_t)t * DIM;
  float4 xv[2];
  float acc[8];
#pragma unroll
  for (int e = 0; e < 8; ++e) acc[e] = 0.f;
#pragma unroll
  for (int h = 0; h < 2; ++h) {
    const int d0 = tid * 4 + h * 1024;
    xv[h] = *(const float4*)&xr[d0];
    const float* wp = &Wr[(size_t)d0 * NE];
    float xe[4] = {xv[h].x, xv[h].y, xv[h].z, xv[h].w};
#pragma unroll
    for (int q = 0; q < 4; ++q) {
      float4 w0 = *(const float4*)&wp[q * 8];
      float4 w1 = *(const float4*)&wp[q * 8 + 4];
      acc[0] += xe[q] * w0.x; acc[1] += xe[q] * w0.y;
      acc[2] += xe[q] * w0.z; acc[3] += xe[q] * w0.w;
      acc[4] += xe[q] * w1.x; acc[5] += xe[q] * w1.y;
      acc[6] += xe[q] * w1.z; acc[7] += xe[q] * w1.w;
    }
  }
#pragma unroll
  for (int e = 0; e < 8; ++e) {
#pragma unroll
    for (int off = 32; off > 0; off >>= 1) acc[e] += __shfl_down(acc[e], off, 64);
  }
  __shared__ float red[4][8];
  __shared__ int sRow[2];
  const int lane = tid & 63, wid = tid >> 6;
  if (lane == 0) {
#pragma unroll
    for (int e = 0; e < 8; ++e) red[wid][e] = acc[e];
  }
  __syncthreads();
  if (tid == 0) {
    float lg[8];
#pragma unroll
    for (int e = 0; e < 8; ++e)
      lg[e] = red[0][e] + red[1][e] + red[2][e] + red[3][e] + br[e];
    int i0 = 0;
#pragma unroll
    for (int e = 1; e < 8; ++e) if (lg[e] > lg[i0]) i0 = e;
    int i1 = (i0 == 0) ? 1 : 0;
#pragma unroll
    for (int e = 0; e < 8; ++e)
      if (e != i0 && lg[e] > lg[i1]) i1 = e;
    const float g0 = 1.f / (1.f + expf(lg[i1] - lg[i0]));
    const float g1 = 1.f - g0;
    const int p0 = atomicAdd(&cnt[i0], 1);
    const int p1 = atomicAdd(&cnt[i1], 1);
    gate_list[i0 * T_TOK + p0] = g0;
    gate_list[i1 * T_TOK + p1] = g1;
    sRow[0] = i0 * EPAD + p0;
    sRow[1] = i1 * EPAD + p1;
    inv[t] = make_int2(sRow[0], sRow[1]);
  }
  __syncthreads();
  const size_t r0 = (size_t)sRow[0] * DIM;
  const size_t r1 = (size_t)sRow[1] * DIM;
#pragma unroll
  for (int h = 0; h < 2; ++h) {
    const int d0 = tid * 4 + h * 1024;
    bf16x4 xc;
    xc[0] = (bf16)xv[h].x; xc[1] = (bf16)xv[h].y;
    xc[2] = (bf16)xv[h].z; xc[3] = (bf16)xv[h].w;
    *(bf16x4*)&xg[r0 + d0] = xc;
    *(bf16x4*)&xg[r1 + d0] = xc;
  }
}

// ===========================================================================
// 256x256 tile, BK=64, 512 threads (8 waves = 2m x 4n, 128x64 out per wave),
// double-buffered LDS, 4-phase/K-tile schedule with COUNTED vmcnt (T3+T4),
// setprio around MFMA clusters (T5), XOR-swizzled LDS (T2, measured 0 confl).
//
// LDS tile [256 r][64 k] bf16 in 16B chunks: row r, k-block kb at position
// kb^(r&7). Staged linear-dest via pre-swizzled global k offset kq.
// Staging passes (2 gld each, 64 rows/pass): A0(r0-63) A1(64-127) A2(128-191)
// A3(192-255); same for B. Per-tile issue order: A0,A2 | B0,B1 | B2,B3 | A1,A3
//   (ph0)     (ph1)   (ph2)   (ph3)
// Reads (wave wm,wn): ph0 needs A0/A2 (its first 4 m-frags) + B[wn] -> the
// first 6 issued loads -> vmcnt(2). ph2 needs A1/A3 (last 2 issued) -> after
// ph0+ph1 issued 4 new loads -> vmcnt(4). ph1/ph3: no waits. Never 0 in loop.
// Correctness: each phase = [wait][s_barrier][ds_read][gld][MFMA]; a wave's
// gld into buf[p] at tile t+1 ph0 is >= 2 barriers after every wave's last
// ds_read of buf[p] (completed before its ph2 MFMA issue).
// ===========================================================================

#define TILE_BODY(LAST)                                                       \
  {                                                                           \
    const bf16* asF = &As[p][0];                                              \
    const bf16* bsF = &Bs[p][0];                                              \
    bf16* asN = &As[p ^ 1][0];                                                \
    bf16* bsN = &Bs[p ^ 1][0];                                                \
    const int kn = (t + 1) * 64;                                              \
    bf16x8 af[4][2], b01[2][2], b23[2][2];                                    \
    /* ---------- phase 0: A-first-half x B[0,1] ---------- */                \
    asm volatile("s_waitcnt vmcnt(2)" ::: "memory");                          \
    __builtin_amdgcn_s_barrier();                                             \
    _Pragma("unroll") for (int i = 0; i < 4; ++i) {                           \
      af[i][0] = *(const bf16x8*)&asF[aoff[i] + xs0];                         \
      af[i][1] = *(const bf16x8*)&asF[aoff[i] + xs1];                         \
    }                                                                         \
    _Pragma("unroll") for (int j = 0; j < 2; ++j) {                           \
      b01[j][0] = *(const bf16x8*)&bsF[boff[j] + xs0];                        \
      b01[j][1] = *(const bf16x8*)&bsF[boff[j] + xs1];                        \
    }                                                                         \
    if (!(LAST)) {                                                            \
      gld_lds16(ap[0] + kn, asN + (size_t)tid * 8);                           \
      gld_lds16(ap[2] + kn, asN + (size_t)(1024 + tid) * 8);                  \
    }                                                                         \
    __builtin_amdgcn_s_setprio(1);                                            \
    _Pragma("unroll") for (int s = 0; s < 2; ++s)                             \
      _Pragma("unroll") for (int i = 0; i < 4; ++i)                           \
        _Pragma("unroll") for (int j = 0; j < 2; ++j)                         \
          acc[i][j] = __builtin_amdgcn_mfma_f32_16x16x32_bf16(                \
              af[i][s], b01[j][s], acc[i][j], 0, 0, 0);                       \
    __builtin_amdgcn_s_setprio(0);                                            \
    /* ---------- phase 1: A-first-half x B[2,3] ---------- */                \
    __builtin_amdgcn_s_barrier();                                             \
    _Pragma("unroll") for (int j = 0; j < 2; ++j) {                           \
      b23[j][0] = *(const bf16x8*)&bsF[boff[j + 2] + xs0];                    \
      b23[j][1] = *(const bf16x8*)&bsF[boff[j + 2] + xs1];                    \
    }                                                                         \
    if (!(LAST)) {                                                            \
      gld_lds16(bp[0] + kn, bsN + (size_t)tid * 8);                           \
      gld_lds16(bp[1] + kn, bsN + (size_t)(512 + tid) * 8);                   \
    }                                                                         \
    __builtin_amdgcn_s_setprio(1);                                            \
    _Pragma("unroll") for (int s = 0; s < 2; ++s)                             \
      _Pragma("unroll") for (int i = 0; i < 4; ++i)                           \
        _Pragma("unroll") for (int j = 0; j < 2; ++j)                         \
          acc[i][j + 2] = __builtin_amdgcn_mfma_f32_16x16x32_bf16(            \
              af[i][s], b23[j][s], acc[i][j + 2], 0, 0, 0);                   \
    __builtin_amdgcn_s_setprio(0);                                            \
    /* ---------- phase 2: A-second-half x B[2,3] ---------- */               \
    if (LAST) { asm volatile("s_waitcnt vmcnt(0)" ::: "memory"); }            \
    else      { asm volatile("s_waitcnt vmcnt(4)" ::: "memory"); }            \
    __builtin_amdgcn_s_barrier();                                             \
    _Pragma("unroll") for (int i = 0; i < 4; ++i) {                           \
      af[i][0] = *(const bf16x8*)&asF[aoff[i + 4] + xs0];                     \
      af[i][1] = *(const bf16x8*)&asF[aoff[i + 4] + xs1];                     \
    }                                                                         \
    if (!(LAST)) {                                                            \
      gld_lds16(bp[2] + kn, bsN + (size_t)(1024 + tid) * 8);                  \
      gld_lds16(bp[3] + kn, bsN + (size_t)(1536 + tid) * 8);                  \
    }                                                                         \
    __builtin_amdgcn_s_setprio(1);                                            \
    _Pragma("unroll") for (int s = 0; s < 2; ++s)                             \
      _Pragma("unroll") for (int i = 0; i < 4; ++i)                           \
        _Pragma("unroll") for (int j = 0; j < 2; ++j)                         \
          acc[i + 4][j + 2] = __builtin_amdgcn_mfma_f32_16x16x32_bf16(        \
              af[i][s], b23[j][s], acc[i + 4][j + 2], 0, 0, 0);               \
    __builtin_amdgcn_s_setprio(0);                                            \
    /* ---------- phase 3: A-second-half x B[0,1] ---------- */               \
    __builtin_amdgcn_s_barrier();                                             \
    if (!(LAST)) {                                                            \
      gld_lds16(ap[1] + kn, asN + (size_t)(512 + tid) * 8);                   \
      gld_lds16(ap[3] + kn, asN + (size_t)(1536 + tid) * 8);                  \
    }                                                                         \
    __builtin_amdgcn_s_setprio(1);                                            \
    _Pragma("unroll") for (int s = 0; s < 2; ++s)                             \
      _Pragma("unroll") for (int i = 0; i < 4; ++i)                           \
        _Pragma("unroll") for (int j = 0; j < 2; ++j)                         \
          acc[i + 4][j] = __builtin_amdgcn_mfma_f32_16x16x32_bf16(            \
              af[i][s], b01[j][s], acc[i + 4][j], 0, 0, 0);                   \
    __builtin_amdgcn_s_setprio(0);                                            \
    p ^= 1;                                                                   \
  }

#define GEMM_SETUP_FRAGS()                                                    \
  const int lane = tid & 63, w = tid >> 6;                                    \
  const int wm = w >> 2, wn = w & 3;                                          \
  const int quad = lane >> 4, l15 = lane & 15;                                \
  const int xs0 = ((quad) ^ (l15 & 7)) * 8;                                   \
  const int xs1 = ((quad + 4) ^ (l15 & 7)) * 8;                               \
  int aoff[8], boff[4];                                                       \
  _Pragma("unroll") for (int i = 0; i < 8; ++i)                               \
      aoff[i] = (wm * 128 + i * 16 + l15) * 64;                               \
  _Pragma("unroll") for (int j = 0; j < 4; ++j)                               \
      boff[j] = (wn * 64 + j * 16 + l15) * 64;                                \
  floatx4 acc[8][4];                                                          \
  _Pragma("unroll") for (int i = 0; i < 8; ++i)                               \
    _Pragma("unroll") for (int j = 0; j < 4; ++j)                             \
        acc[i][j] = (floatx4){0.f, 0.f, 0.f, 0.f};

#define GEMM_PROLOGUE()                                                       \
  gld_lds16(ap[0], &As[0][(size_t)tid * 8]);                                  \
  gld_lds16(ap[2], &As[0][(size_t)(1024 + tid) * 8]);                         \
  gld_lds16(bp[0], &Bs[0][(size_t)tid * 8]);                                  \
  gld_lds16(bp[1], &Bs[0][(size_t)(512 + tid) * 8]);                          \
  gld_lds16(bp[2], &Bs[0][(size_t)(1024 + tid) * 8]);                         \
  gld_lds16(bp[3], &Bs[0][(size_t)(1536 + tid) * 8]);                         \
  gld_lds16(ap[1], &As[0][(size_t)(512 + tid) * 8]);                          \
  gld_lds16(ap[3], &As[0][(size_t)(1536 + tid) * 8]);                         \
  int p = 0;                                                                  \
  int t = 0;                                                                  \
  for (; t < NTIL - 1; ++t) TILE_BODY(0);                                     \
  TILE_BODY(1);

// ---- grouped expert GEMM, dense A: H = silu(xg[e] @ We[e]^T + be)*gate ----
__global__ __launch_bounds__(512, 2) void expert_gemm(
    const bf16* __restrict__ xg, const bf16* __restrict__ Wt,
    const float* __restrict__ be, const int* __restrict__ cnt,
    const float* __restrict__ gate_list, bf16* __restrict__ aoutc) {
  // bijective XCD swizzle over 576 = 72*8 blocks: XCD k gets contiguous cids
  const int b = blockIdx.x;
  const int wg = (b & 7) * MAXC + (b >> 3);
  const int cid = wg >> 3;
  int e = -1, m0 = 0, total = 0;
#pragma unroll
  for (int q = 0; q < NE; ++q) {
    const int c = (cnt[q] + 255) >> 8;
    if (e < 0 && cid < total + c) { e = q; m0 = (cid - total) * 256; }
    total += c;
  }
  if (e < 0 || cid >= total) return;
  const int ne = cnt[e];
  const int n0 = (wg & 7) * 256;
  const int tid = threadIdx.x;

  __shared__ bf16 As[2][256 * 64];
  __shared__ bf16 Bs[2][256 * 64];
  __shared__ float gateS[256];

  if (tid < 256)
    gateS[tid] = (m0 + tid < ne) ? gate_list[e * T_TOK + m0 + tid] : 0.f;

  const int r0 = tid >> 3;
  const int kq = ((tid & 7) ^ (r0 & 7)) * 8;
  const bf16* wbase = Wt + (size_t)e * DIM * DIM;
  const bf16* abase = xg + (size_t)(e * EPAD + m0) * DIM;
  const bf16* ap[4];
  const bf16* bp[4];
#pragma unroll
  for (int h = 0; h < 4; ++h) {
    const int r = r0 + 64 * h;
    ap[h] = abase + (size_t)r * DIM + kq;  // rows >= ne read garbage; their
    bp[h] = wbase + (size_t)(n0 + r) * DIM + kq;  // outputs are masked below
  }

  GEMM_SETUP_FRAGS()
  GEMM_PROLOGUE()

  // epilogue: + be, silu, * gate, dense store
#pragma unroll
  for (int j = 0; j < 4; ++j) {
    const int col = n0 + wn * 64 + j * 16 + l15;
    const float bev = be[e * DIM + col];
#pragma unroll
    for (int i = 0; i < 8; ++i) {
#pragma unroll
      for (int r = 0; r < 4; ++r) {
        const int rl = wm * 128 + i * 16 + quad * 4 + r;
        if (m0 + rl < ne) {
          float v = acc[i][j][r] + bev;
          v = v / (1.f + __expf(-v));
          v *= gateS[rl];
          aoutc[(size_t)(e * EPAD + m0 + rl) * DIM + col] = (bf16)v;
        }
      }
    }
  }
}

// ---- combine: hcomb[t] = aoutc[inv[t].x] + aoutc[inv[t].y] (bf16) ----
__global__ __launch_bounds__(256) void combine_kernel(
    const bf16* __restrict__ aoutc, const int2* __restrict__ inv,
    bf16* __restrict__ hcomb) {
  const int t = blockIdx.x;
  const int2 iv = inv[t];
  const int d = threadIdx.x * 8;
  bf16x8 u0 = *(const bf16x8*)&aoutc[(size_t)iv.x * DIM + d];
  bf16x8 u1 = *(const bf16x8*)&aoutc[(size_t)iv.y * DIM + d];
  bf16x8 s;
#pragma unroll
  for (int q = 0; q < 8; ++q) s[q] = (bf16)((float)u0[q] + (float)u1[q]);
  *(bf16x8*)&hcomb[(size_t)t * DIM + d] = s;
}

// ---- output projection: y = hcomb @ Wo + bo + x (fp32), same 8-phase core ----
__global__ __launch_bounds__(512, 2) void proj_gemm(
    const bf16* __restrict__ hcomb, const bf16* __restrict__ Wot,
    const float* __restrict__ bo, const float* __restrict__ x,
    float* __restrict__ y) {
  const int b = blockIdx.x;
  const int wg = (b & 7) * 32 + (b >> 3);  // 256 = 32*8 bijective
  const int m0 = (wg >> 3) * 256;
  const int n0 = (wg & 7) * 256;
  const int tid = threadIdx.x;

  __shared__ bf16 As[2][256 * 64];
  __shared__ bf16 Bs[2][256 * 64];

  const int r0 = tid >> 3;
  const int kq = ((tid & 7) ^ (r0 & 7)) * 8;
  const bf16* ap[4];
  const bf16* bp[4];
#pragma unroll
  for (int h = 0; h < 4; ++h) {
    const int r = r0 + 64 * h;
    ap[h] = hcomb + (size_t)(m0 + r) * DIM + kq;
    bp[h] = Wot + (size_t)(n0 + r) * DIM + kq;
  }

  GEMM_SETUP_FRAGS()
  GEMM_PROLOGUE()

#pragma unroll
  for (int j = 0; j < 4; ++j) {
    const int col = n0 + wn * 64 + j * 16 + l15;
    const float bov = bo[col];
#pragma unroll
    for (int i = 0; i < 8; ++i) {
#pragma unroll
      for (int r = 0; r < 4; ++r) {
        const int rl = wm * 128 + i * 16 + quad * 4 + r;
        const size_t o = (size_t)(m0 + rl) * DIM + col;
        y[o] = acc[i][j][r] + bov + x[o];
      }
    }
  }
}

// ---- in-place RMSNorm over rows of d_out ----
__global__ __launch_bounds__(256) void rmsnorm_kernel(
    float* __restrict__ y, const float* __restrict__ w) {
  const int row = blockIdx.x;
  const int tid = threadIdx.x;
  float* yr = y + (size_t)row * DIM;
  float4 v0 = ((const float4*)yr)[tid];
  float4 v1 = ((const float4*)yr)[tid + 256];
  float ss = v0.x * v0.x + v0.y * v0.y + v0.z * v0.z + v0.w * v0.w +
             v1.x * v1.x + v1.y * v1.y + v1.z * v1.z + v1.w * v1.w;
#pragma unroll
  for (int off = 32; off > 0; off >>= 1) ss += __shfl_down(ss, off, 64);
  __shared__ float s4[4];
  const int lane = tid & 63, wid = tid >> 6;
  if (lane == 0) s4[wid] = ss;
  __syncthreads();
  const float tot = s4[0] + s4[1] + s4[2] + s4[3];
  const float r = rsqrtf(tot / (float)DIM + 1e-6f);
  float4 w0 = ((const float4*)w)[tid];
  float4 w1 = ((const float4*)w)[tid + 256];
  float4 o0 = make_float4(v0.x * r * w0.x, v0.y * r * w0.y, v0.z * r * w0.z, v0.w * r * w0.w);
  float4 o1 = make_float4(v1.x * r * w1.x, v1.y * r * w1.y, v1.z * r * w1.z, v1.w * r * w1.w);
  ((float4*)yr)[tid] = o0;
  ((float4*)yr)[tid + 256] = o1;
}

extern "C" void kernel_launch(void* const* d_in, const int* in_sizes, int n_in,
                              void* d_out, int out_size, void* d_ws, size_t ws_size,
                              hipStream_t stream) {
  const float* x  = (const float*)d_in[0];
  const float* Wr = (const float*)d_in[1];
  const float* br = (const float*)d_in[2];
  const float* We = (const float*)d_in[3];
  const float* be = (const float*)d_in[4];
  const float* Wo = (const float*)d_in[5];
  const float* bo = (const float*)d_in[6];
  const float* nw = (const float*)d_in[7];
  float* out = (float*)d_out;

  uint8_t* ws = (uint8_t*)d_ws;
  size_t off = 0;
  auto carve = [&](size_t bytes) -> void* {
    void* p = ws + off;
    off += (bytes + 255) & ~(size_t)255;
    return p;
  };
  int*   cnt       = (int*)carve(NE * sizeof(int));
  float* gate_list = (float*)carve((size_t)NE * T_TOK * sizeof(float));
  int2*  inv       = (int2*)carve((size_t)T_TOK * sizeof(int2));
  bf16*  We_t      = (bf16*)carve((size_t)NE * DIM * DIM * sizeof(bf16));
  bf16*  Wo_t      = (bf16*)carve((size_t)DIM * DIM * sizeof(bf16));
  bf16*  xg        = (bf16*)carve((size_t)NE * EPAD * DIM * sizeof(bf16));
  bf16*  aoutc     = (bf16*)carve((size_t)NE * EPAD * DIM * sizeof(bf16));
  // hcomb aliases We_t: dead after expert_gemm; combine/proj run strictly later
  bf16*  hcomb     = We_t;
  (void)ws_size; (void)in_sizes; (void)n_in; (void)out_size;

  transpose_convert<<<dim3(32, 32, 9), 256, 0, stream>>>(We, Wo, We_t, Wo_t, cnt);
  router_kernel<<<T_TOK, 256, 0, stream>>>(x, Wr, br, cnt, gate_list, inv, xg);
  expert_gemm<<<dim3(MAXC * 8), 512, 0, stream>>>(xg, We_t, be, cnt, gate_list, aoutc);
  combine_kernel<<<T_TOK, 256, 0, stream>>>(aoutc, inv, hcomb);
  proj_gemm<<<dim3(32 * 8), 512, 0, stream>>>(hcomb, Wo_t, bo, x, out);
  rmsnorm_kernel<<<T_TOK, 256, 0, stream>>>(out, nw);
}